// Round 15
// baseline (362.346 us; speedup 1.0000x reference)
//
#include <hip/hip_runtime.h>

// ---------------- constants ----------------
// B=8, C=32, CO=32, NIN=16, NOUT=10, D1=D2=512, NRC=1344
#define OUT_ZW1 2097152u
#define OUT_ZW2 69206016u
#define OUT_U0  70516736u
#define OUT_U1  70647808u
#define OUT_U2  70778880u

// workspace layout (floats) — no global atomics
#define WS_RM1P   0u        // [4][256][512] w1 col-sum partials
#define WS_CM1    524288u
#define WS_CM0    655360u
#define WS_RM2    786432u
#define WS_RCW1   917504u   // [4][256]
#define WS_RC     918528u   // [8][1344]
#define WS_RTERM  929280u
#define WS_CTERM  1060352u
#define WS_W0T    1191424u  // [8][512][512], ends 3288576
#define WS_TW0    3288576u
#define WS_TB0    3292672u
#define WS_TL1    3292928u
#define WS_TBIAS1 3293184u
#define WS_TFIN   3293440u  // ends 3296000
#define WS_RM1F   3296000u  // [256][512] combined w1 col-sums

static __device__ __forceinline__ float wave_reduce(float v) {
#pragma unroll
  for (int off = 32; off > 0; off >>= 1) v += __shfl_down(v, off);
  return v;
}

#define FMA8x2(ACC_A, ACC_B, WA, WB, XA, XB)                                        \
  ACC_A[0] += WA.x * XA; ACC_A[1] += WA.y * XA; ACC_A[2] += WA.z * XA;              \
  ACC_A[3] += WA.w * XA; ACC_A[4] += WB.x * XA; ACC_A[5] += WB.y * XA;              \
  ACC_A[6] += WB.z * XA; ACC_A[7] += WB.w * XA;                                     \
  ACC_B[0] += WA.x * XB; ACC_B[1] += WA.y * XB; ACC_B[2] += WA.z * XB;              \
  ACC_B[3] += WA.w * XB; ACC_B[4] += WB.x * XB; ACC_B[5] += WB.y * XB;              \
  ACC_B[6] += WB.z * XB; ACC_B[7] += WB.w * XB;

// ---- K1: small stats [0,256) | w1 stats [256,1280) | w0 transpose [1280,1536) ----
__global__ __launch_bounds__(256) void ksetup(
    const float* __restrict__ w0, const float* __restrict__ w2,
    const float* __restrict__ b0, const float* __restrict__ b1,
    const float* __restrict__ b2, const float* __restrict__ w1,
    float* __restrict__ ws) {
  __shared__ float sred[16];
  __shared__ float stot;
  __shared__ float rpart[512];
  __shared__ float swsum[4];
  int tid = threadIdx.x, lane = tid & 63;
  int bx = blockIdx.x;

  if (bx < 256) {
    int bc = bx;
    int b = bc >> 5, c = bc & 31;
    float* rcb = ws + WS_RC + b * 1344;
    float* cm0 = ws + WS_CM0;
    float* rm2 = ws + WS_RM2;

    if (tid < 16) sred[tid] = 0.f;
    if (tid == 0) stot = 0.f;
    __syncthreads();
    {
      float rm0p[16];
#pragma unroll
      for (int k = 0; k < 16; ++k) rm0p[k] = 0.f;
      float tot = 0.f;
      for (int d = tid; d < 512; d += 256) {
        const float4* p = (const float4*)(w0 + ((size_t)bc * 512 + d) * 16);
        float s = 0.f;
#pragma unroll
        for (int q = 0; q < 4; ++q) {
          float4 v = p[q];
          s += v.x + v.y + v.z + v.w;
          rm0p[q * 4 + 0] += v.x; rm0p[q * 4 + 1] += v.y;
          rm0p[q * 4 + 2] += v.z; rm0p[q * 4 + 3] += v.w;
        }
        cm0[(size_t)bc * 512 + d] = s * (1.f / 16.f);
        tot += s;
      }
#pragma unroll
      for (int k = 0; k < 16; ++k) {
        float r = wave_reduce(rm0p[k]);
        if (lane == 0) atomicAdd(&sred[k], r);  // LDS atomic (intra-block only)
      }
      float rt = wave_reduce(tot);
      if (lane == 0) atomicAdd(&stot, rt);
    }
    __syncthreads();
    if (tid < 16) rcb[192 + c * 16 + tid] = sred[tid] * (1.f / 512.f);
    if (tid == 0) rcb[c] = stot * (1.f / 8192.f);
    __syncthreads();

    if (tid < 10) sred[tid] = 0.f;
    if (tid == 0) stot = 0.f;
    __syncthreads();
    {
      float cm2p[10];
#pragma unroll
      for (int k = 0; k < 10; ++k) cm2p[k] = 0.f;
      float tot = 0.f;
      for (int d = tid; d < 512; d += 256) {
        float s = 0.f;
#pragma unroll
        for (int k = 0; k < 10; ++k) {
          float v = w2[((size_t)bc * 10 + k) * 512 + d];
          s += v; cm2p[k] += v;
        }
        rm2[(size_t)bc * 512 + d] = s * 0.1f;
        tot += s;
      }
#pragma unroll
      for (int k = 0; k < 10; ++k) {
        float r = wave_reduce(cm2p[k]);
        if (lane == 0) atomicAdd(&sred[k], r);
      }
      float rt = wave_reduce(tot);
      if (lane == 0) atomicAdd(&stot, rt);
    }
    __syncthreads();
    if (tid < 10) rcb[704 + c * 10 + tid] = sred[tid] * (1.f / 512.f);
    if (tid == 0) rcb[64 + c] = stot * (1.f / 5120.f);
    __syncthreads();

    if (tid < 2) sred[tid] = 0.f;
    __syncthreads();
    {
      float t0 = 0.f, t1 = 0.f;
      for (int d = tid; d < 512; d += 256) {
        t0 += b0[(size_t)bc * 512 + d];
        t1 += b1[(size_t)bc * 512 + d];
      }
      t0 = wave_reduce(t0); t1 = wave_reduce(t1);
      if (lane == 0) { atomicAdd(&sred[0], t0); atomicAdd(&sred[1], t1); }
    }
    __syncthreads();
    if (tid == 0) {
      rcb[96 + c] = sred[0] * (1.f / 512.f);
      rcb[128 + c] = sred[1] * (1.f / 512.f);
    }

    float vb2 = 0.f;
    if (tid < 10) {
      vb2 = b2[bc * 10 + tid];
      rcb[1024 + c * 10 + tid] = vb2;
    }
    if (tid < 64) {
      float s = wave_reduce(vb2);
      if (tid == 0) rcb[160 + c] = s * 0.1f;
    }
  } else if (bx < 1280) {
    int idx = bx - 256;
    int bc = idx >> 2, hc = idx & 3;
    int wid = tid >> 6;
    const float* base = w1 + (size_t)bc * 262144 + (size_t)hc * 65536;
    float col0 = 0.f, col1 = 0.f;
    for (int hl = 0; hl < 128; ++hl) {
      float2 x = *(const float2*)(base + hl * 512 + 2 * tid);
      col0 += x.x; col1 += x.y;
      float r = wave_reduce(x.x + x.y);
      if (lane == 0) rpart[hl * 4 + wid] = r;
    }
    __syncthreads();
    if (tid < 128) {
      float s = rpart[tid * 4] + rpart[tid * 4 + 1] + rpart[tid * 4 + 2] + rpart[tid * 4 + 3];
      ws[WS_CM1 + (size_t)bc * 512 + hc * 128 + tid] = s * (1.f / 512.f);
    }
    ws[WS_RM1P + (size_t)hc * 131072 + (size_t)bc * 512 + 2 * tid] = col0;
    ws[WS_RM1P + (size_t)hc * 131072 + (size_t)bc * 512 + 2 * tid + 1] = col1;
    float bt = wave_reduce(col0 + col1);
    if (lane == 0) swsum[wid] = bt;
    __syncthreads();
    if (tid == 0)
      ws[WS_RCW1 + hc * 256 + bc] = swsum[0] + swsum[1] + swsum[2] + swsum[3];
  } else {
    int bc = bx - 1280;
    int b = bc >> 5, c = bc & 31;
    for (int dd = 0; dd < 2; ++dd) {
      int d = tid + dd * 256;
      const float4* src = (const float4*)(w0 + ((size_t)bc * 512 + d) * 16);
      float4 v0 = src[0], v1 = src[1], v2 = src[2], v3 = src[3];
      float vals[16] = {v0.x, v0.y, v0.z, v0.w, v1.x, v1.y, v1.z, v1.w,
                        v2.x, v2.y, v2.z, v2.w, v3.x, v3.y, v3.z, v3.w};
#pragma unroll
      for (int k = 0; k < 16; ++k)
        ws[WS_W0T + ((size_t)(b * 512 + c * 16 + k)) * 512 + d] = vals[k];
    }
  }
}

// ---- K2: rc projections [0,2496) XCD-swizzled (b = blk%8) + rm1 combine [2496,3008) ----
__global__ __launch_bounds__(256) void krcgemm(
    float* __restrict__ ws,
    const float* __restrict__ W_w0_rc, const float* __restrict__ B_w0_rc,
    const float* __restrict__ W_b0_rc, const float* __restrict__ B_b0_rc,
    const float* __restrict__ W_l1_rc, const float* __restrict__ B_l1_rc,
    const float* __restrict__ W_bias1_rc, const float* __restrict__ B_bias1_rc,
    const float* __restrict__ W_fin_rc, const float* __restrict__ B_fin_rc,
    const float* __restrict__ W_bfin_rc, const float* __restrict__ B_bfin_rc,
    float* __restrict__ u2out) {
  int blk = blockIdx.x, tid = threadIdx.x;
  if (blk >= 2496) {
    int i = (blk - 2496) * 256 + tid;  // 131072 = 512*256
    ws[WS_RM1F + i] = ws[WS_RM1P + i] + ws[WS_RM1P + 131072 + i] +
                      ws[WS_RM1P + 262144 + i] + ws[WS_RM1P + 393216 + i];
    return;
  }
  // XCD swizzle: same weight rows across the 8 batches land on the same XCD L2.
  int b = blk & 7;
  int rg = blk >> 3;  // 0..311
  int lane = tid & 63, wid = tid >> 6;
  int r = rg * 4 + wid;
  __shared__ float rcs[1344];
  for (int j = tid; j < 1344; j += 256)
    if (j < 32 || j >= 64) rcs[j] = ws[WS_RC + b * 1344 + j];
  if (tid < 32)
    rcs[32 + tid] = (ws[WS_RCW1 + 0 * 256 + b * 32 + tid] +
                     ws[WS_RCW1 + 1 * 256 + b * 32 + tid] +
                     ws[WS_RCW1 + 2 * 256 + b * 32 + tid] +
                     ws[WS_RCW1 + 3 * 256 + b * 32 + tid]) * (1.f / 262144.f);
  __syncthreads();
  const float* W; const float* Bb; float* dst; int row;
  if (r < 512)      { W = W_w0_rc;    Bb = B_w0_rc;    row = r;       dst = ws + WS_TW0 + b * 512; }
  else if (r < 544) { W = W_b0_rc;    Bb = B_b0_rc;    row = r - 512; dst = ws + WS_TB0 + b * 32; }
  else if (r < 576) { W = W_l1_rc;    Bb = B_l1_rc;    row = r - 544; dst = ws + WS_TL1 + b * 32; }
  else if (r < 608) { W = W_bias1_rc; Bb = B_bias1_rc; row = r - 576; dst = ws + WS_TBIAS1 + b * 32; }
  else if (r < 928) { W = W_fin_rc;   Bb = B_fin_rc;   row = r - 608; dst = ws + WS_TFIN + b * 320; }
  else              { W = W_bfin_rc;  Bb = B_bfin_rc;  row = r - 928; dst = u2out + b * 320; }
  const float* wr = W + (size_t)row * 1344;
  float acc = 0.f;
  for (int j = lane; j < 1344; j += 64) acc += wr[j] * rcs[j];
  acc = wave_reduce(acc);
  if (lane == 0) dst[row] = acc + Bb[row];
}

// ---- K3: LDS-tiled GEMMs, XCD-swizzled so same-batch blocks share an XCD L2.
// rterm [0,32) | cterm+u1 [32,64) | z0/u0 [64,608) | zf [608,928); b = t%8 everywhere.
__global__ __launch_bounds__(256) void kbig(
    const float* __restrict__ rm1, const float* __restrict__ cm0,
    const float* __restrict__ b0, const float* __restrict__ w0T,
    const float* __restrict__ W_l1_r, const float* __restrict__ B_l1_r,
    float* __restrict__ rterm,
    const float* __restrict__ cm1, const float* __restrict__ b1,
    const float* __restrict__ rm2, const float* __restrict__ w2,
    const float* __restrict__ W_l1_c, const float* __restrict__ B_l1_c,
    const float* __restrict__ B_l1, const float* __restrict__ t_l1,
    const float* __restrict__ W_bias1, const float* __restrict__ B_bias1,
    const float* __restrict__ t_bias1,
    float* __restrict__ cterm_full, float* __restrict__ u1out,
    const float* __restrict__ W_w0_rpt, const float* __restrict__ B_rpt,
    const float* __restrict__ W_b0, const float* __restrict__ B_b0w,
    const float* __restrict__ t_w0, const float* __restrict__ t_b0,
    const float* __restrict__ W_fin_cpt, const float* __restrict__ B_fin,
    const float* __restrict__ t_fin, float* __restrict__ out) {
  __shared__ float xt[8192];    // 16 x 512 x-tile (32 KB)
  __shared__ float wch[256];    // chunk weights (dual for cterm)
  __shared__ float wext[1536];  // extra-row weights (dual for cterm)
  int bid = blockIdx.x, tid = threadIdx.x;
  int d = 2 * tid;

#define CHUNK_LOOP(NCH, XP, WSRC, WLEN, WOFF)                                       \
  for (int ch = 0; ch < (NCH); ++ch) {                                              \
    const float4* g4 = (const float4*)((XP) + (size_t)ch * 16 * 512);               \
    float4* x4 = (float4*)xt;                                                       \
    _Pragma("unroll")                                                               \
    for (int k = 0; k < 8; ++k) x4[tid + k * 256] = g4[tid + k * 256];              \
    if (tid < 128) {                                                                \
      int i = tid >> 3, oo = tid & 7;                                               \
      wch[tid] = (WSRC)[(size_t)(o0 + oo) * (WLEN) + (WOFF) + ch * 16 + i];         \
    }                                                                               \
    __syncthreads();                                                                \
    _Pragma("unroll")                                                               \
    for (int i = 0; i < 16; ++i) {                                                  \
      float2 xv = *(const float2*)&xt[i * 512 + d];                                 \
      float4 wa = *(const float4*)&wch[i * 8];                                      \
      float4 wb = *(const float4*)&wch[i * 8 + 4];                                  \
      FMA8x2(aA, aB, wa, wb, xv.x, xv.y)                                            \
    }                                                                               \
    __syncthreads();                                                                \
  }

  if (bid < 32) {
    // ======== rterm: b = bid%8, oy = bid/8 (XCD swizzle) ========
    int b = bid & 7, oy = bid >> 3;
    int o0 = oy * 8;
    for (int idx = tid; idx < 768; idx += 256) {
      int i = idx >> 3, oo = idx & 7;
      wext[idx] = W_l1_r[(size_t)(o0 + oo) * 608 + i];
    }
    float aA[8] = {0, 0, 0, 0, 0, 0, 0, 0};
    float aB[8] = {0, 0, 0, 0, 0, 0, 0, 0};
    const float* xp = w0T + (size_t)b * 512 * 512;
    CHUNK_LOOP(32, xp, W_l1_r, 608, 96)
#pragma unroll 4
    for (int i = 0; i < 32; ++i) {
      float2 xv = *(const float2*)(rm1 + ((size_t)b * 32 + i) * 512 + d);
      float xa = xv.x * (1.f / 512.f), xb = xv.y * (1.f / 512.f);
      float4 wa = *(const float4*)&wext[i * 8];
      float4 wb = *(const float4*)&wext[i * 8 + 4];
      FMA8x2(aA, aB, wa, wb, xa, xb)
    }
#pragma unroll 4
    for (int i = 0; i < 32; ++i) {
      float2 xv = *(const float2*)(cm0 + ((size_t)b * 32 + i) * 512 + d);
      float4 wa = *(const float4*)&wext[(32 + i) * 8];
      float4 wb = *(const float4*)&wext[(32 + i) * 8 + 4];
      FMA8x2(aA, aB, wa, wb, xv.x, xv.y)
    }
#pragma unroll 4
    for (int i = 0; i < 32; ++i) {
      float2 xv = *(const float2*)(b0 + ((size_t)b * 32 + i) * 512 + d);
      float4 wa = *(const float4*)&wext[(64 + i) * 8];
      float4 wb = *(const float4*)&wext[(64 + i) * 8 + 4];
      FMA8x2(aA, aB, wa, wb, xv.x, xv.y)
    }
#pragma unroll
    for (int oo = 0; oo < 8; ++oo) {
      int o = o0 + oo;
      float bb = B_l1_r[o];
      *(float2*)(rterm + ((size_t)b * 32 + o) * 512 + d) = make_float2(aA[oo] + bb, aB[oo] + bb);
    }
  } else if (bid < 64) {
    // ======== cterm+u1: b = t%8, oy = t/8 ========
    int t = bid - 32;
    int b = t & 7, oy = t >> 3;
    int o0 = oy * 8;
    for (int idx = tid; idx < 768; idx += 256) {
      int i = idx >> 3, oo = idx & 7;
      wext[idx] = W_l1_c[(size_t)(o0 + oo) * 416 + i];
      wext[768 + idx] = W_bias1[(size_t)(o0 + oo) * 416 + i];
    }
    float aA[8] = {0, 0, 0, 0, 0, 0, 0, 0};
    float aB[8] = {0, 0, 0, 0, 0, 0, 0, 0};
    float uA[8] = {0, 0, 0, 0, 0, 0, 0, 0};
    float uB[8] = {0, 0, 0, 0, 0, 0, 0, 0};
    const float* xp = w2 + (size_t)b * 320 * 512;
    for (int ch = 0; ch < 20; ++ch) {
      const float4* g4 = (const float4*)(xp + (size_t)ch * 16 * 512);
      float4* x4 = (float4*)xt;
#pragma unroll
      for (int k = 0; k < 8; ++k) x4[tid + k * 256] = g4[tid + k * 256];
      if (tid < 128) {
        int i = tid >> 3, oo = tid & 7;
        wch[tid] = W_l1_c[(size_t)(o0 + oo) * 416 + 96 + ch * 16 + i];
        wch[128 + tid] = W_bias1[(size_t)(o0 + oo) * 416 + 96 + ch * 16 + i];
      }
      __syncthreads();
#pragma unroll
      for (int i = 0; i < 16; ++i) {
        float2 xv = *(const float2*)&xt[i * 512 + d];
        float4 wa = *(const float4*)&wch[i * 8];
        float4 wb = *(const float4*)&wch[i * 8 + 4];
        float4 va = *(const float4*)&wch[128 + i * 8];
        float4 vb = *(const float4*)&wch[128 + i * 8 + 4];
        FMA8x2(aA, aB, wa, wb, xv.x, xv.y)
        FMA8x2(uA, uB, va, vb, xv.x, xv.y)
      }
      __syncthreads();
    }
#pragma unroll 2
    for (int i = 0; i < 32; ++i) {
      float2 xv = *(const float2*)(cm1 + ((size_t)b * 32 + i) * 512 + d);
      float4 wa = *(const float4*)&wext[i * 8];
      float4 wb = *(const float4*)&wext[i * 8 + 4];
      float4 va = *(const float4*)&wext[768 + i * 8];
      float4 vb = *(const float4*)&wext[768 + i * 8 + 4];
      FMA8x2(aA, aB, wa, wb, xv.x, xv.y)
      FMA8x2(uA, uB, va, vb, xv.x, xv.y)
    }
#pragma unroll 2
    for (int i = 0; i < 32; ++i) {
      float2 xv = *(const float2*)(b1 + ((size_t)b * 32 + i) * 512 + d);
      float4 wa = *(const float4*)&wext[(32 + i) * 8];
      float4 wb = *(const float4*)&wext[(32 + i) * 8 + 4];
      float4 va = *(const float4*)&wext[768 + (32 + i) * 8];
      float4 vb = *(const float4*)&wext[768 + (32 + i) * 8 + 4];
      FMA8x2(aA, aB, wa, wb, xv.x, xv.y)
      FMA8x2(uA, uB, va, vb, xv.x, xv.y)
    }
#pragma unroll 2
    for (int i = 0; i < 32; ++i) {
      float2 xv = *(const float2*)(rm2 + ((size_t)b * 32 + i) * 512 + d);
      float4 wa = *(const float4*)&wext[(64 + i) * 8];
      float4 wb = *(const float4*)&wext[(64 + i) * 8 + 4];
      float4 va = *(const float4*)&wext[768 + (64 + i) * 8];
      float4 vb = *(const float4*)&wext[768 + (64 + i) * 8 + 4];
      FMA8x2(aA, aB, wa, wb, xv.x, xv.y)
      FMA8x2(uA, uB, va, vb, xv.x, xv.y)
    }
#pragma unroll
    for (int oo = 0; oo < 8; ++oo) {
      int o = o0 + oo;
      float cb = B_l1_c[o] + B_l1[o] + t_l1[b * 32 + o];
      float ub = B_bias1[o] + t_bias1[b * 32 + o];
      *(float2*)(cterm_full + ((size_t)b * 32 + o) * 512 + d) = make_float2(aA[oo] + cb, aB[oo] + cb);
      *(float2*)(u1out + ((size_t)b * 32 + o) * 512 + d) = make_float2(uA[oo] + ub, uB[oo] + ub);
    }
  } else if (bid < 608) {
    // ======== z0/u0: b = t%8, oc = t/8 (544 = 68x8) ========
    int t = bid - 64;
    int b = t & 7, oc = t >> 3;
    bool isZ = oc < 64;
    int o0 = isZ ? oc * 8 : (oc - 64) * 8;
    const float* Wsrc = isZ ? W_w0_rpt : W_b0;
    for (int idx = tid; idx < 512; idx += 256) {
      int i = idx >> 3, oo = idx & 7;
      wext[idx] = Wsrc[(size_t)(o0 + oo) * 576 + 512 + i];
    }
    float aA[8] = {0, 0, 0, 0, 0, 0, 0, 0};
    float aB[8] = {0, 0, 0, 0, 0, 0, 0, 0};
    const float* xp = w0T + (size_t)b * 512 * 512;
    CHUNK_LOOP(32, xp, Wsrc, 576, 0)
#pragma unroll 4
    for (int i = 0; i < 32; ++i) {
      float2 xv = *(const float2*)(rm1 + ((size_t)b * 32 + i) * 512 + d);
      float xa = xv.x * (1.f / 512.f), xb = xv.y * (1.f / 512.f);
      float4 wa = *(const float4*)&wext[i * 8];
      float4 wb = *(const float4*)&wext[i * 8 + 4];
      FMA8x2(aA, aB, wa, wb, xa, xb)
    }
#pragma unroll 4
    for (int i = 0; i < 32; ++i) {
      float2 xv = *(const float2*)(b0 + ((size_t)b * 32 + i) * 512 + d);
      float4 wa = *(const float4*)&wext[(32 + i) * 8];
      float4 wb = *(const float4*)&wext[(32 + i) * 8 + 4];
      FMA8x2(aA, aB, wa, wb, xv.x, xv.y)
    }
    if (isZ) {
#pragma unroll
      for (int oo = 0; oo < 8; ++oo) {
        int o = o0 + oo, co = o >> 4, k = o & 15;
        float bb = B_rpt[o] + t_w0[b * 512 + o];
        size_t base = (((size_t)b * 32 + co) * 512 + d) * 16 + k;
        out[base] = aA[oo] + bb;
        out[base + 16] = aB[oo] + bb;
      }
    } else {
#pragma unroll
      for (int oo = 0; oo < 8; ++oo) {
        int o = o0 + oo;
        float bb = B_b0w[o] + t_b0[b * 32 + o];
        *(float2*)(out + OUT_U0 + ((size_t)b * 32 + o) * 512 + d) =
            make_float2(aA[oo] + bb, aB[oo] + bb);
      }
    }
  } else {
    // ======== zf: b = t%8, oc = t/8 (320 = 40x8) ========
    int t = bid - 608;
    int b = t & 7, oc = t >> 3;
    int o0 = oc * 8;
    for (int idx = tid; idx < 256; idx += 256) {
      int i = idx >> 3, oo = idx & 7;
      wext[idx] = W_fin_cpt[(size_t)(o0 + oo) * 352 + 320 + i];
    }
    float aA[8] = {0, 0, 0, 0, 0, 0, 0, 0};
    float aB[8] = {0, 0, 0, 0, 0, 0, 0, 0};
    const float* xp = w2 + (size_t)b * 320 * 512;
    CHUNK_LOOP(20, xp, W_fin_cpt, 352, 0)
#pragma unroll 4
    for (int i = 0; i < 32; ++i) {
      float2 xv = *(const float2*)(cm1 + ((size_t)b * 32 + i) * 512 + d);
      float4 wa = *(const float4*)&wext[i * 8];
      float4 wb = *(const float4*)&wext[i * 8 + 4];
      FMA8x2(aA, aB, wa, wb, xv.x, xv.y)
    }
#pragma unroll
    for (int oo = 0; oo < 8; ++oo) {
      int o = o0 + oo;
      float bb = B_fin[o] + t_fin[b * 320 + o];
      *(float2*)(out + OUT_ZW2 + ((size_t)b * 320 + o) * 512 + d) =
          make_float2(aA[oo] + bb, aB[oo] + bb);
    }
  }
#undef CHUNK_LOOP
}

// ---- K4: zw1 = W_l1 . w1 + rterm + cterm (float4, 2 rows/block, W_l1^T in LDS) ----
__global__ __launch_bounds__(256) void kzw1(
    const float* __restrict__ w1, const float* __restrict__ W_l1,
    const float* __restrict__ rterm, const float* __restrict__ cterm,
    float* __restrict__ out) {
  __shared__ float wl[1024];
  int hp = blockIdx.x, b = blockIdx.y;
  int t = threadIdx.x;
  for (int i = t; i < 1024; i += 256) wl[(i & 31) * 32 + (i >> 5)] = W_l1[i];
  __syncthreads();
  int h0 = hp * 2;
  int hoff = t >> 7;
  int w = (t & 127) * 4;
  float4 acc[32];
#pragma unroll
  for (int o = 0; o < 32; ++o) acc[o] = make_float4(0.f, 0.f, 0.f, 0.f);
  const float* src = w1 + ((size_t)b * 32 * 512 + h0) * 512 + 4 * t;
#pragma unroll 4
  for (int i = 0; i < 32; ++i) {
    float4 x = *(const float4*)(src + (size_t)i * 262144);
    const float* wp = wl + i * 32;
#pragma unroll
    for (int o = 0; o < 32; ++o) {
      acc[o].x += wp[o] * x.x;
      acc[o].y += wp[o] * x.y;
      acc[o].z += wp[o] * x.z;
      acc[o].w += wp[o] * x.w;
    }
  }
  int h = h0 + hoff;
#pragma unroll
  for (int o = 0; o < 32; ++o) {
    float cf = cterm[((size_t)b * 32 + o) * 512 + h];
    float4 rt = *(const float4*)(rterm + ((size_t)b * 32 + o) * 512 + w);
    float4 res = make_float4(acc[o].x + rt.x + cf, acc[o].y + rt.y + cf,
                             acc[o].z + rt.z + cf, acc[o].w + rt.w + cf);
    *(float4*)(out + (size_t)OUT_ZW1 + (((size_t)b * 32 + o) * 512 + h) * 512 + w) = res;
  }
}

extern "C" void kernel_launch(void* const* d_in, const int* in_sizes, int n_in,
                              void* d_out, int out_size, void* d_ws, size_t ws_size,
                              hipStream_t stream) {
  const float* w0 = (const float*)d_in[0];
  const float* w1 = (const float*)d_in[1];
  const float* w2 = (const float*)d_in[2];
  const float* b0 = (const float*)d_in[3];
  const float* b1 = (const float*)d_in[4];
  const float* b2 = (const float*)d_in[5];
  const float* W_w0_rpt = (const float*)d_in[6];
  const float* B_w0_rpt = (const float*)d_in[7];
  const float* W_w0_rc = (const float*)d_in[8];
  const float* B_w0_rc = (const float*)d_in[9];
  const float* W_b0 = (const float*)d_in[10];
  const float* B_b0 = (const float*)d_in[11];
  const float* W_b0_rc = (const float*)d_in[12];
  const float* B_b0_rc = (const float*)d_in[13];
  const float* W_l1 = (const float*)d_in[14];
  const float* B_l1 = (const float*)d_in[15];
  const float* W_l1_rc = (const float*)d_in[16];
  const float* B_l1_rc = (const float*)d_in[17];
  const float* W_l1_r = (const float*)d_in[18];
  const float* B_l1_r = (const float*)d_in[19];
  const float* W_l1_c = (const float*)d_in[20];
  const float* B_l1_c = (const float*)d_in[21];
  const float* W_bias1 = (const float*)d_in[22];
  const float* B_bias1 = (const float*)d_in[23];
  const float* W_bias1_rc = (const float*)d_in[24];
  const float* B_bias1_rc = (const float*)d_in[25];
  const float* W_fin_cpt = (const float*)d_in[26];
  const float* B_fin_cpt = (const float*)d_in[27];
  const float* W_fin_rc = (const float*)d_in[28];
  const float* B_fin_rc = (const float*)d_in[29];
  const float* W_bfin_rc = (const float*)d_in[30];
  const float* B_bfin_rc = (const float*)d_in[31];
  float* ws = (float*)d_ws;
  float* out = (float*)d_out;

  ksetup<<<dim3(1536), 256, 0, stream>>>(w0, w2, b0, b1, b2, w1, ws);

  krcgemm<<<dim3(3008), 256, 0, stream>>>(
      ws, W_w0_rc, B_w0_rc, W_b0_rc, B_b0_rc, W_l1_rc, B_l1_rc, W_bias1_rc,
      B_bias1_rc, W_fin_rc, B_fin_rc, W_bfin_rc, B_bfin_rc, out + OUT_U2);

  kbig<<<dim3(928), 256, 0, stream>>>(
      ws + WS_RM1F, ws + WS_CM0, b0, ws + WS_W0T, W_l1_r, B_l1_r, ws + WS_RTERM,
      ws + WS_CM1, b1, ws + WS_RM2, w2, W_l1_c, B_l1_c, B_l1, ws + WS_TL1, W_bias1,
      B_bias1, ws + WS_TBIAS1, ws + WS_CTERM, out + OUT_U1,
      W_w0_rpt, B_w0_rpt, W_b0, B_b0, ws + WS_TW0, ws + WS_TB0,
      W_fin_cpt, B_fin_cpt, ws + WS_TFIN, out);

  kzw1<<<dim3(256, 8), 256, 0, stream>>>(w1, W_l1, ws + WS_RTERM, ws + WS_CTERM, out);
  (void)in_sizes; (void)n_in; (void)out_size; (void)ws_size;
}

// Round 16
// 296.499 us; speedup vs baseline: 1.2221x; 1.2221x over previous
//
#include <hip/hip_runtime.h>

typedef unsigned short ushortT;
typedef __attribute__((ext_vector_type(8))) short bf16x8;
typedef __attribute__((ext_vector_type(4))) float f32x4;

// ---------------- constants ----------------
// B=8, C=32, CO=32, NIN=16, NOUT=10, D1=D2=512, NRC=1344
#define OUT_ZW1 2097152u
#define OUT_ZW2 69206016u
#define OUT_U0  70516736u
#define OUT_U1  70647808u
#define OUT_U2  70778880u

// fp32 workspace (floats)
#define WS_RM1P   0u        // [4][256][512] w1 col-sum partials
#define WS_RCW1   917504u   // [4][256]
#define WS_RC     918528u   // [8][1344]
#define WS_RTERM  929280u
#define WS_CTERM  1060352u
#define WS_TW0    3288576u
#define WS_TB0    3292672u
#define WS_TL1    3292928u
#define WS_TBIAS1 3293184u
#define WS_TFIN   3293440u

// bf16 panels, stored in the zw1 output region (overwritten by kzw1 afterwards).
// offsets in ushorts:
#define PZ0  0u         // [8][576][512]
#define PRT  2359296u   // [8][608][512]
#define PCT  4849664u   // [8][416][512]
#define PZF  6553600u   // [8][352][512]
#define PWZ0 7995392u   // [544][576]
#define PWRT 8308736u   // [32][608]
#define PWCT 8328192u   // [64][416]
#define PWZF 8354816u   // [320][352]

static __device__ __forceinline__ float wave_reduce(float v) {
#pragma unroll
  for (int off = 32; off > 0; off >>= 1) v += __shfl_down(v, off);
  return v;
}

static __device__ __forceinline__ ushortT f2bf(float f) {
  unsigned u = __float_as_uint(f);
  u += 0x7FFFu + ((u >> 16) & 1u);
  return (ushortT)(u >> 16);
}

// ---- K1: stats [0,256) | w1 stats [256,1280) | w0->bf16 panels [1280,1536) |
//          weight bf16 conversion [1536,3380) ----
__global__ __launch_bounds__(256) void ksetup(
    const float* __restrict__ w0, const float* __restrict__ w2,
    const float* __restrict__ b0, const float* __restrict__ b1,
    const float* __restrict__ b2, const float* __restrict__ w1,
    const float* __restrict__ W_w0_rpt, const float* __restrict__ W_b0,
    const float* __restrict__ W_l1_r, const float* __restrict__ W_l1_c,
    const float* __restrict__ W_bias1, const float* __restrict__ W_fin_cpt,
    float* __restrict__ ws, ushortT* __restrict__ pan) {
  __shared__ float sred[16];
  __shared__ float stot;
  __shared__ float rpart[512];
  __shared__ float swsum[4];
  int tid = threadIdx.x, lane = tid & 63;
  int bx = blockIdx.x;

  if (bx < 256) {
    int bc = bx;
    int b = bc >> 5, c = bc & 31;
    float* rcb = ws + WS_RC + b * 1344;

    if (tid < 16) sred[tid] = 0.f;
    if (tid == 0) stot = 0.f;
    __syncthreads();
    {
      float rm0p[16];
#pragma unroll
      for (int k = 0; k < 16; ++k) rm0p[k] = 0.f;
      float tot = 0.f;
      for (int d = tid; d < 512; d += 256) {
        const float4* p = (const float4*)(w0 + ((size_t)bc * 512 + d) * 16);
        float s = 0.f;
#pragma unroll
        for (int q = 0; q < 4; ++q) {
          float4 v = p[q];
          s += v.x + v.y + v.z + v.w;
          rm0p[q * 4 + 0] += v.x; rm0p[q * 4 + 1] += v.y;
          rm0p[q * 4 + 2] += v.z; rm0p[q * 4 + 3] += v.w;
        }
        pan[PRT + ((size_t)(b * 608 + 32 + c)) * 512 + d] = f2bf(s * (1.f / 16.f));
        tot += s;
      }
#pragma unroll
      for (int k = 0; k < 16; ++k) {
        float r = wave_reduce(rm0p[k]);
        if (lane == 0) atomicAdd(&sred[k], r);  // LDS atomic (intra-block only)
      }
      float rt = wave_reduce(tot);
      if (lane == 0) atomicAdd(&stot, rt);
    }
    __syncthreads();
    if (tid < 16) rcb[192 + c * 16 + tid] = sred[tid] * (1.f / 512.f);
    if (tid == 0) rcb[c] = stot * (1.f / 8192.f);
    __syncthreads();

    if (tid < 10) sred[tid] = 0.f;
    if (tid == 0) stot = 0.f;
    __syncthreads();
    {
      float cm2p[10];
#pragma unroll
      for (int k = 0; k < 10; ++k) cm2p[k] = 0.f;
      float tot = 0.f;
      for (int d = tid; d < 512; d += 256) {
        float s = 0.f;
#pragma unroll
        for (int k = 0; k < 10; ++k) {
          float v = w2[((size_t)bc * 10 + k) * 512 + d];
          s += v; cm2p[k] += v;
          ushortT bv = f2bf(v);
          pan[PCT + ((size_t)(b * 416 + 96 + c * 10 + k)) * 512 + d] = bv;
          pan[PZF + ((size_t)(b * 352 + c * 10 + k)) * 512 + d] = bv;
        }
        pan[PCT + ((size_t)(b * 416 + 64 + c)) * 512 + d] = f2bf(s * 0.1f);
        tot += s;
      }
#pragma unroll
      for (int k = 0; k < 10; ++k) {
        float r = wave_reduce(cm2p[k]);
        if (lane == 0) atomicAdd(&sred[k], r);
      }
      float rt = wave_reduce(tot);
      if (lane == 0) atomicAdd(&stot, rt);
    }
    __syncthreads();
    if (tid < 10) rcb[704 + c * 10 + tid] = sred[tid] * (1.f / 512.f);
    if (tid == 0) rcb[64 + c] = stot * (1.f / 5120.f);
    __syncthreads();

    if (tid < 2) sred[tid] = 0.f;
    __syncthreads();
    {
      float t0 = 0.f, t1 = 0.f;
      for (int d = tid; d < 512; d += 256) {
        float vb0 = b0[(size_t)bc * 512 + d];
        float vb1 = b1[(size_t)bc * 512 + d];
        t0 += vb0; t1 += vb1;
        ushortT h0 = f2bf(vb0);
        pan[PRT + ((size_t)(b * 608 + 64 + c)) * 512 + d] = h0;
        pan[PZ0 + ((size_t)(b * 576 + 544 + c)) * 512 + d] = h0;
        pan[PCT + ((size_t)(b * 416 + 32 + c)) * 512 + d] = f2bf(vb1);
      }
      t0 = wave_reduce(t0); t1 = wave_reduce(t1);
      if (lane == 0) { atomicAdd(&sred[0], t0); atomicAdd(&sred[1], t1); }
    }
    __syncthreads();
    if (tid == 0) {
      rcb[96 + c] = sred[0] * (1.f / 512.f);
      rcb[128 + c] = sred[1] * (1.f / 512.f);
    }

    float vb2 = 0.f;
    if (tid < 10) {
      vb2 = b2[bc * 10 + tid];
      rcb[1024 + c * 10 + tid] = vb2;
    }
    if (tid < 64) {
      float s = wave_reduce(vb2);
      if (tid == 0) rcb[160 + c] = s * 0.1f;
    }
  } else if (bx < 1280) {
    int idx = bx - 256;
    int bc = idx >> 2, hc = idx & 3;
    int b = bc >> 5, c = bc & 31;
    int wid = tid >> 6;
    const float* base = w1 + (size_t)bc * 262144 + (size_t)hc * 65536;
    float col0 = 0.f, col1 = 0.f;
    for (int hl = 0; hl < 128; ++hl) {
      float2 x = *(const float2*)(base + hl * 512 + 2 * tid);
      col0 += x.x; col1 += x.y;
      float r = wave_reduce(x.x + x.y);
      if (lane == 0) rpart[hl * 4 + wid] = r;
    }
    __syncthreads();
    if (tid < 128) {
      float s = rpart[tid * 4] + rpart[tid * 4 + 1] + rpart[tid * 4 + 2] + rpart[tid * 4 + 3];
      ushortT m = f2bf(s * (1.f / 512.f));
      pan[PCT + ((size_t)(b * 416 + c)) * 512 + hc * 128 + tid] = m;
      pan[PZF + ((size_t)(b * 352 + 320 + c)) * 512 + hc * 128 + tid] = m;
    }
    ws[WS_RM1P + (size_t)hc * 131072 + (size_t)bc * 512 + 2 * tid] = col0;
    ws[WS_RM1P + (size_t)hc * 131072 + (size_t)bc * 512 + 2 * tid + 1] = col1;
    float bt = wave_reduce(col0 + col1);
    if (lane == 0) swsum[wid] = bt;
    __syncthreads();
    if (tid == 0)
      ws[WS_RCW1 + hc * 256 + bc] = swsum[0] + swsum[1] + swsum[2] + swsum[3];
  } else if (bx < 1536) {
    // ---- w0 -> bf16 panels (xz0 rows 0..511, xrt rows 96..607) ----
    int bc = bx - 1280;
    int b = bc >> 5, c = bc & 31;
    for (int dd = 0; dd < 2; ++dd) {
      int d = tid + dd * 256;
      const float4* src = (const float4*)(w0 + ((size_t)bc * 512 + d) * 16);
      float4 v0 = src[0], v1 = src[1], v2 = src[2], v3 = src[3];
      float vals[16] = {v0.x, v0.y, v0.z, v0.w, v1.x, v1.y, v1.z, v1.w,
                        v2.x, v2.y, v2.z, v2.w, v3.x, v3.y, v3.z, v3.w};
#pragma unroll
      for (int k = 0; k < 16; ++k) {
        ushortT h = f2bf(vals[k]);
        pan[PZ0 + ((size_t)(b * 576 + c * 16 + k)) * 512 + d] = h;
        pan[PRT + ((size_t)(b * 608 + 96 + c * 16 + k)) * 512 + d] = h;
      }
    }
  } else {
    // ---- weight bf16 conversions ----
    int g = bx - 1536;
    int idx = g * 256 + tid;
    if (g < 1224) {                       // Wz0 [544][576]
      int o = idx / 576, kk = idx - o * 576;
      float v = (o < 512) ? W_w0_rpt[idx] : W_b0[(size_t)(o - 512) * 576 + kk];
      pan[PWZ0 + idx] = f2bf(v);
    } else if (g < 1300) {                // Wrt [32][608]
      int j = idx - 313344;
      pan[PWRT + j] = f2bf(W_l1_r[j]);
    } else if (g < 1404) {                // Wct [64][416]
      int j = idx - 332800;
      int o = j / 416, kk = j - o * 416;
      float v = (o < 32) ? W_l1_c[j] : W_bias1[(size_t)(o - 32) * 416 + kk];
      pan[PWCT + j] = f2bf(v);
    } else {                              // Wzf [320][352]
      int j = idx - 359424;
      pan[PWZF + j] = f2bf(W_fin_cpt[j]);
    }
  }
}

// ---- K2: rc projections [0,2496) + rm1 combine -> bf16 panel rows [2496,3008) ----
__global__ __launch_bounds__(256) void krcgemm(
    float* __restrict__ ws, ushortT* __restrict__ pan,
    const float* __restrict__ W_w0_rc, const float* __restrict__ B_w0_rc,
    const float* __restrict__ W_b0_rc, const float* __restrict__ B_b0_rc,
    const float* __restrict__ W_l1_rc, const float* __restrict__ B_l1_rc,
    const float* __restrict__ W_bias1_rc, const float* __restrict__ B_bias1_rc,
    const float* __restrict__ W_fin_rc, const float* __restrict__ B_fin_rc,
    const float* __restrict__ W_bfin_rc, const float* __restrict__ B_bfin_rc,
    float* __restrict__ u2out) {
  int blk = blockIdx.x, tid = threadIdx.x;
  if (blk >= 2496) {
    int i = (blk - 2496) * 256 + tid;  // 131072 = 256*512
    int bc = i >> 9, d = i & 511;
    int b = bc >> 5, c = bc & 31;
    float s = ws[WS_RM1P + i] + ws[WS_RM1P + 131072 + i] +
              ws[WS_RM1P + 262144 + i] + ws[WS_RM1P + 393216 + i];
    ushortT m = f2bf(s * (1.f / 512.f));
    pan[PZ0 + ((size_t)(b * 576 + 512 + c)) * 512 + d] = m;
    pan[PRT + ((size_t)(b * 608 + c)) * 512 + d] = m;
    return;
  }
  int b = blk & 7;
  int rg = blk >> 3;
  int lane = tid & 63, wid = tid >> 6;
  int r = rg * 4 + wid;
  __shared__ float rcs[1344];
  for (int j = tid; j < 1344; j += 256)
    if (j < 32 || j >= 64) rcs[j] = ws[WS_RC + b * 1344 + j];
  if (tid < 32)
    rcs[32 + tid] = (ws[WS_RCW1 + 0 * 256 + b * 32 + tid] +
                     ws[WS_RCW1 + 1 * 256 + b * 32 + tid] +
                     ws[WS_RCW1 + 2 * 256 + b * 32 + tid] +
                     ws[WS_RCW1 + 3 * 256 + b * 32 + tid]) * (1.f / 262144.f);
  __syncthreads();
  const float* W; const float* Bb; float* dst; int row;
  if (r < 512)      { W = W_w0_rc;    Bb = B_w0_rc;    row = r;       dst = ws + WS_TW0 + b * 512; }
  else if (r < 544) { W = W_b0_rc;    Bb = B_b0_rc;    row = r - 512; dst = ws + WS_TB0 + b * 32; }
  else if (r < 576) { W = W_l1_rc;    Bb = B_l1_rc;    row = r - 544; dst = ws + WS_TL1 + b * 32; }
  else if (r < 608) { W = W_bias1_rc; Bb = B_bias1_rc; row = r - 576; dst = ws + WS_TBIAS1 + b * 32; }
  else if (r < 928) { W = W_fin_rc;   Bb = B_fin_rc;   row = r - 608; dst = ws + WS_TFIN + b * 320; }
  else              { W = W_bfin_rc;  Bb = B_bfin_rc;  row = r - 928; dst = u2out + b * 320; }
  const float* wr = W + (size_t)row * 1344;
  float acc = 0.f;
  for (int j = lane; j < 1344; j += 64) acc += wr[j] * rcs[j];
  acc = wave_reduce(acc);
  if (lane == 0) dst[row] = acc + Bb[row];
}

// ---- K3: MFMA GEMMs. z0/u0 [0,576) | rterm [576,640) | cterm/u1 [640,704) | zf [704,1024)
// block = 64o x 64d tile, 4 waves (wave w: rows 16w..16w+15), K in 32-chunks via LDS.
__global__ __launch_bounds__(256) void kgemm(
    const ushortT* __restrict__ pan,
    const float* __restrict__ B_rpt, const float* __restrict__ t_w0,
    const float* __restrict__ B_b0w, const float* __restrict__ t_b0,
    const float* __restrict__ B_l1_r,
    const float* __restrict__ B_l1_c, const float* __restrict__ B_l1,
    const float* __restrict__ t_l1,
    const float* __restrict__ B_bias1, const float* __restrict__ t_bias1,
    const float* __restrict__ B_fin, const float* __restrict__ t_fin,
    float* __restrict__ rterm, float* __restrict__ cterm,
    float* __restrict__ u1out, float* __restrict__ out) {
  __shared__ __align__(16) ushortT als[64 * 40];
  __shared__ __align__(16) ushortT bls[64 * 40];
  int bid = blockIdx.x, tid = threadIdx.x;
  int w = tid >> 6, lane = tid & 63;

  const ushortT *X, *W;
  int K, M, o0, d0, b, mode;
  if (bid < 576) {
    int t = bid; b = t & 7; int r = t >> 3; int mt = r % 9, dt = r / 9;
    X = pan + PZ0 + (size_t)b * 576 * 512; W = pan + PWZ0;
    K = 576; M = 544; o0 = mt * 64; d0 = dt * 64; mode = 0;
  } else if (bid < 640) {
    int t = bid - 576; b = t & 7; int dt = t >> 3;
    X = pan + PRT + (size_t)b * 608 * 512; W = pan + PWRT;
    K = 608; M = 32; o0 = 0; d0 = dt * 64; mode = 1;
  } else if (bid < 704) {
    int t = bid - 640; b = t & 7; int dt = t >> 3;
    X = pan + PCT + (size_t)b * 416 * 512; W = pan + PWCT;
    K = 416; M = 64; o0 = 0; d0 = dt * 64; mode = 2;
  } else {
    int t = bid - 704; b = t & 7; int r = t >> 3; int mt = r % 5, dt = r / 5;
    X = pan + PZF + (size_t)b * 352 * 512; W = pan + PWZF;
    K = 352; M = 320; o0 = mt * 64; d0 = dt * 64; mode = 3;
  }

  f32x4 acc[4];
#pragma unroll
  for (int s = 0; s < 4; ++s) acc[s] = (f32x4){0.f, 0.f, 0.f, 0.f};

  int ar = tid >> 2, ap = tid & 3;  // A staging: 64 rows x 4 parts of 8 ushorts
  int arow = o0 + ar; if (arow > M - 1) arow = M - 1;
  int bk = tid >> 3, bg = tid & 7;  // B staging: 32 k x 8 d-groups

  for (int kk = 0; kk < K; kk += 32) {
    *(uint4*)&als[ar * 40 + ap * 8] = *(const uint4*)&W[(size_t)arow * K + kk + ap * 8];
    uint4 v = *(const uint4*)&X[(size_t)(kk + bk) * 512 + d0 + bg * 8];
    const ushortT* pv = (const ushortT*)&v;
#pragma unroll
    for (int jj = 0; jj < 8; ++jj) bls[(bg * 8 + jj) * 40 + bk] = pv[jj];
    __syncthreads();
    bf16x8 a = *(const bf16x8*)&als[(w * 16 + (lane & 15)) * 40 + (lane >> 4) * 8];
#pragma unroll
    for (int s = 0; s < 4; ++s) {
      bf16x8 bb = *(const bf16x8*)&bls[(s * 16 + (lane & 15)) * 40 + (lane >> 4) * 8];
      acc[s] = __builtin_amdgcn_mfma_f32_16x16x32_bf16(a, bb, acc[s], 0, 0, 0);
    }
    __syncthreads();
  }

  int col = lane & 15, rg2 = lane >> 4;
#pragma unroll
  for (int s = 0; s < 4; ++s) {
    int d = d0 + s * 16 + col;
#pragma unroll
    for (int r = 0; r < 4; ++r) {
      int o = o0 + w * 16 + rg2 * 4 + r;
      float v = acc[s][r];
      if (mode == 0) {
        if (o < 512) {
          int co = o >> 4, k2 = o & 15;
          out[(((size_t)b * 32 + co) * 512 + d) * 16 + k2] = v + B_rpt[o] + t_w0[b * 512 + o];
        } else if (o < 544) {
          int oo = o - 512;
          out[OUT_U0 + ((size_t)b * 32 + oo) * 512 + d] = v + B_b0w[oo] + t_b0[b * 32 + oo];
        }
      } else if (mode == 1) {
        if (o < 32) rterm[((size_t)b * 32 + o) * 512 + d] = v + B_l1_r[o];
      } else if (mode == 2) {
        if (o < 32) {
          cterm[((size_t)b * 32 + o) * 512 + d] = v + B_l1_c[o] + B_l1[o] + t_l1[b * 32 + o];
        } else {
          int oo = o - 32;
          u1out[((size_t)b * 32 + oo) * 512 + d] = v + B_bias1[oo] + t_bias1[b * 32 + oo];
        }
      } else {
        out[OUT_ZW2 + ((size_t)b * 320 + o) * 512 + d] = v + B_fin[o] + t_fin[b * 320 + o];
      }
    }
  }
}

// ---- K4: zw1 = W_l1 . w1 + rterm + cterm (fp32; HBM-bound) ----
__global__ __launch_bounds__(256) void kzw1(
    const float* __restrict__ w1, const float* __restrict__ W_l1,
    const float* __restrict__ rterm, const float* __restrict__ cterm,
    float* __restrict__ out) {
  __shared__ float wl[1024];
  int hp = blockIdx.x, b = blockIdx.y;
  int t = threadIdx.x;
  for (int i = t; i < 1024; i += 256) wl[(i & 31) * 32 + (i >> 5)] = W_l1[i];
  __syncthreads();
  int h0 = hp * 2;
  int hoff = t >> 7;
  int w = (t & 127) * 4;
  float4 acc[32];
#pragma unroll
  for (int o = 0; o < 32; ++o) acc[o] = make_float4(0.f, 0.f, 0.f, 0.f);
  const float* src = w1 + ((size_t)b * 32 * 512 + h0) * 512 + 4 * t;
#pragma unroll 4
  for (int i = 0; i < 32; ++i) {
    float4 x = *(const float4*)(src + (size_t)i * 262144);
    const float* wp = wl + i * 32;
#pragma unroll
    for (int o = 0; o < 32; ++o) {
      acc[o].x += wp[o] * x.x;
      acc[o].y += wp[o] * x.y;
      acc[o].z += wp[o] * x.z;
      acc[o].w += wp[o] * x.w;
    }
  }
  int h = h0 + hoff;
#pragma unroll
  for (int o = 0; o < 32; ++o) {
    float cf = cterm[((size_t)b * 32 + o) * 512 + h];
    float4 rt = *(const float4*)(rterm + ((size_t)b * 32 + o) * 512 + w);
    float4 res = make_float4(acc[o].x + rt.x + cf, acc[o].y + rt.y + cf,
                             acc[o].z + rt.z + cf, acc[o].w + rt.w + cf);
    *(float4*)(out + (size_t)OUT_ZW1 + (((size_t)b * 32 + o) * 512 + h) * 512 + w) = res;
  }
}

extern "C" void kernel_launch(void* const* d_in, const int* in_sizes, int n_in,
                              void* d_out, int out_size, void* d_ws, size_t ws_size,
                              hipStream_t stream) {
  const float* w0 = (const float*)d_in[0];
  const float* w1 = (const float*)d_in[1];
  const float* w2 = (const float*)d_in[2];
  const float* b0 = (const float*)d_in[3];
  const float* b1 = (const float*)d_in[4];
  const float* b2 = (const float*)d_in[5];
  const float* W_w0_rpt = (const float*)d_in[6];
  const float* B_w0_rpt = (const float*)d_in[7];
  const float* W_w0_rc = (const float*)d_in[8];
  const float* B_w0_rc = (const float*)d_in[9];
  const float* W_b0 = (const float*)d_in[10];
  const float* B_b0 = (const float*)d_in[11];
  const float* W_b0_rc = (const float*)d_in[12];
  const float* B_b0_rc = (const float*)d_in[13];
  const float* W_l1 = (const float*)d_in[14];
  const float* B_l1 = (const float*)d_in[15];
  const float* W_l1_rc = (const float*)d_in[16];
  const float* B_l1_rc = (const float*)d_in[17];
  const float* W_l1_r = (const float*)d_in[18];
  const float* B_l1_r = (const float*)d_in[19];
  const float* W_l1_c = (const float*)d_in[20];
  const float* B_l1_c = (const float*)d_in[21];
  const float* W_bias1 = (const float*)d_in[22];
  const float* B_bias1 = (const float*)d_in[23];
  const float* W_bias1_rc = (const float*)d_in[24];
  const float* B_bias1_rc = (const float*)d_in[25];
  const float* W_fin_cpt = (const float*)d_in[26];
  const float* B_fin_cpt = (const float*)d_in[27];
  const float* W_fin_rc = (const float*)d_in[28];
  const float* B_fin_rc = (const float*)d_in[29];
  const float* W_bfin_rc = (const float*)d_in[30];
  const float* B_bfin_rc = (const float*)d_in[31];
  float* ws = (float*)d_ws;
  float* out = (float*)d_out;
  ushortT* pan = (ushortT*)(out + OUT_ZW1);  // scratch inside zw1 region (16.9 MB),
                                             // fully overwritten by kzw1 afterwards.

  ksetup<<<dim3(3380), 256, 0, stream>>>(w0, w2, b0, b1, b2, w1, W_w0_rpt, W_b0,
                                         W_l1_r, W_l1_c, W_bias1, W_fin_cpt, ws, pan);

  krcgemm<<<dim3(3008), 256, 0, stream>>>(
      ws, pan, W_w0_rc, B_w0_rc, W_b0_rc, B_b0_rc, W_l1_rc, B_l1_rc, W_bias1_rc,
      B_bias1_rc, W_fin_rc, B_fin_rc, W_bfin_rc, B_bfin_rc, out + OUT_U2);

  kgemm<<<dim3(1024), 256, 0, stream>>>(
      pan, B_w0_rpt, ws + WS_TW0, B_b0, ws + WS_TB0, B_l1_r, B_l1_c, B_l1,
      ws + WS_TL1, B_bias1, ws + WS_TBIAS1, B_fin_cpt, ws + WS_TFIN,
      ws + WS_RTERM, ws + WS_CTERM, out + OUT_U1, out);

  kzw1<<<dim3(256, 8), 256, 0, stream>>>(w1, W_l1, ws + WS_RTERM, ws + WS_CTERM, out);
  (void)in_sizes; (void)n_in; (void)out_size; (void)ws_size;
}